// Round 1
// baseline (411.562 us; speedup 1.0000x reference)
//
#include <hip/hip_runtime.h>
#include <math.h>

#define B_   16
#define T_   2048
#define DIM_ 512
#define M_   (B_*T_)

__device__ __forceinline__ float clamp01(float x){ return fminf(fmaxf(x,0.f),1.f); }
__device__ __forceinline__ float clampf(float x,float lo,float hi){ return fminf(fmaxf(x,lo),hi); }
__device__ __forceinline__ float gelu_exact(float x){ return 0.5f*x*(1.f+erff(x*0.70710678118654752f)); }

// ---------------------------------------------------------------------------
// K1: per-batch-row EMA scan (affine wave-scan) + exclusive cumsum(speech)
// grid = B blocks of 64 lanes; lane l owns t in [l*32, l*32+32)
// ---------------------------------------------------------------------------
__global__ __launch_bounds__(64) void k_scan(
    const float* __restrict__ log_anchor, const float* __restrict__ unit_mask,
    const float* __restrict__ sealed_mask, const float* __restrict__ silence_mask,
    const float* __restrict__ local_rate_ema,
    float* __restrict__ lr_seq, float* __restrict__ prefix_prev)
{
  const int b = blockIdx.x, lane = threadIdx.x;
  const float CE = (float)(1.0 - 0.95);   // matches JAX f32 rounding of (1-DECAY)
  const int base = b*T_ + lane*32;

  // local affine composition r_out = A*r_in + Bv, and local speech sum S
  float A = 1.f, Bv = 0.f, S = 0.f;
  for (int j = 0; j < 32; ++j){
    int idx = base + j;
    float mask   = clamp01(unit_mask[idx]);
    float sealed = clamp01(sealed_mask[idx]);
    float sil    = clamp01(silence_mask[idx])*mask;
    float speech = mask*sealed*(1.f-sil);
    float o  = log_anchor[idx];
    float cm = CE*speech;
    A  = (1.f-cm)*A;
    Bv = (1.f-cm)*Bv + cm*o;
    S += speech;
  }
  // inclusive scan across 64 lanes (compose earlier-first)
  float Ai=A, Bi=Bv, Si=S;
  for (int off = 1; off < 64; off <<= 1){
    float Ap=__shfl_up(Ai,off), Bp=__shfl_up(Bi,off), Sp=__shfl_up(Si,off);
    if (lane >= off){ Bi = Ai*Bp + Bi; Ai *= Ap; Si += Sp; }
  }
  // exclusive
  float Ae=__shfl_up(Ai,1), Be=__shfl_up(Bi,1), Se=__shfl_up(Si,1);
  if (lane==0){ Ae=1.f; Be=0.f; Se=0.f; }

  float r  = Ae*local_rate_ema[b] + Be;
  float ps = Se;
  for (int j = 0; j < 32; ++j){
    int idx = base + j;
    float mask   = clamp01(unit_mask[idx]);
    float sealed = clamp01(sealed_mask[idx]);
    float sil    = clamp01(silence_mask[idx])*mask;
    float speech = mask*sealed*(1.f-sil);
    float o = log_anchor[idx];
    lr_seq[idx]      = r;    // value BEFORE update (scan emits carry-before)
    prefix_prev[idx] = ps;   // exclusive cumsum == max(cumsum-speech, 0)
    r  += CE*speech*(o-r);
    ps += speech;
  }
}

// ---------------------------------------------------------------------------
// K2a: spk_ctx[b,d] = tanh(spk_embed[b,:] @ spk_W[:,d] + spk_b[d])
// ---------------------------------------------------------------------------
__global__ __launch_bounds__(512) void k_spkctx(
    const float* __restrict__ spk_embed, const float* __restrict__ spk_W,
    const float* __restrict__ spk_b, float* __restrict__ spk_ctx)
{
  __shared__ float se[512];
  const int b = blockIdx.x, n = threadIdx.x;
  se[n] = spk_embed[b*512 + n];
  __syncthreads();
  float acc = spk_b[n];
  #pragma unroll 8
  for (int k = 0; k < 512; ++k) acc = fmaf(se[k], spk_W[k*512 + n], acc);
  spk_ctx[b*512 + n] = tanhf(acc);
}

// ---------------------------------------------------------------------------
// K2b: spk_term[b,n] = spk_ctx[b,:] @ rW1[512:1024, n]   (rb1 added later)
//      coarse[b]     = 0.2*tanh( gelu(cctx@cW1+cb1) @ cW2 + cb2 )
// ---------------------------------------------------------------------------
__global__ __launch_bounds__(512) void k_coarse_spkterm(
    const float* __restrict__ spk_ctx, const float* __restrict__ global_rate,
    const float* __restrict__ cW1, const float* __restrict__ cb1,
    const float* __restrict__ cW2, const float* __restrict__ cb2,
    const float* __restrict__ rW1,
    float* __restrict__ spk_term, float* __restrict__ coarse)
{
  __shared__ float sc[512];
  __shared__ float red[512];
  const int b = blockIdx.x, n = threadIdx.x;
  sc[n] = spk_ctx[b*512 + n];
  __syncthreads();
  float ac = cb1[n], as = 0.f;
  #pragma unroll 8
  for (int k = 0; k < 512; ++k){
    float s = sc[k];
    ac = fmaf(s, cW1[k*512 + n], ac);
    as = fmaf(s, rW1[(512 + k)*512 + n], as);
  }
  ac = fmaf(global_rate[b], cW1[512*512 + n], ac);   // g_ref row of cW1
  spk_term[b*512 + n] = as;
  red[n] = gelu_exact(ac) * cW2[n];
  __syncthreads();
  for (int s = 256; s > 0; s >>= 1){
    if (n < s) red[n] += red[n + s];
    __syncthreads();
  }
  if (n == 0) coarse[b] = 0.2f*tanhf(red[0] + cb2[0]);
}

// ---------------------------------------------------------------------------
// K3: fused heavy kernel.
//   query (computed on the fly) @ rW1[0:512]  -> + spk_term + gt*rW1[1024] + rb1
//   -> gelu -> dot rW2 -> residual -> final elementwise combine
// Block: 256 threads (16x16), tile 64 rows x 128 cols, K-tile 32, N-chunks x4.
// ---------------------------------------------------------------------------
#define MT 64
#define NT 128
#define KT 32

__global__ __launch_bounds__(256) void k_heavy(
    const int*   __restrict__ content_units, const float* __restrict__ log_anchor,
    const float* __restrict__ unit_mask,     const float* __restrict__ sealed_mask,
    const float* __restrict__ sep_hint,      const float* __restrict__ edge_cue,
    const float* __restrict__ global_rate,   const float* __restrict__ silence_mask,
    const float* __restrict__ embed,         const float* __restrict__ feat_W,
    const float* __restrict__ feat_b,        const float* __restrict__ rW1,
    const float* __restrict__ rb1,           const float* __restrict__ rW2,
    const float* __restrict__ rb2,
    const float* __restrict__ lr_seq,        const float* __restrict__ prefix_prev,
    const float* __restrict__ spk_term,      const float* __restrict__ coarse,
    float* __restrict__ out)
{
  __shared__ __align__(16) float As[KT][MT+4];   // transposed: [k][row]
  __shared__ __align__(16) float Bs[KT][NT+4];
  __shared__ float r_la[MT], r_lr[MT], r_sil[MT], r_sep[MT], r_edge[MT], r_mask[MT];
  __shared__ int   r_u[MT];
  __shared__ float r_gt[MT], r_speech[MT], r_silc[MT], r_resmul[MT], r_tau[MT];
  __shared__ float fw_s[5][KT];
  __shared__ float fb_s[KT];

  const int m0  = blockIdx.x*MT;
  const int b   = m0 >> 11;          // / T_
  const int tid = threadIdx.x;
  const int tx  = tid & 15, ty = tid >> 4;

  if (tid < MT){
    int m = m0 + tid;
    float mask   = clamp01(unit_mask[m]);
    float sealed = clamp01(sealed_mask[m]);
    float sil    = clamp01(silence_mask[m])*mask;
    float commit = mask*sealed;
    float silc   = commit*sil;
    float speech = commit*(1.f-sil);
    float la = log_anchor[m];
    float lr = lr_seq[m];
    float gap = clampf(global_rate[b]-lr, -0.35f, 0.35f)*commit;
    float gt  = (gap + coarse[b]*commit)*commit;
    float cold = clamp01(prefix_prev[m]*0.5f);          // /COLD_RUNS
    float dur  = expf(la);
    float shortv = clamp01(fmaxf(dur,1.f)-1.f);         // /max(1,MIN_DUR-1)=1
    r_la[tid]=la; r_lr[tid]=lr; r_sil[tid]=sil;
    r_sep[tid]=sep_hint[m]; r_edge[tid]=edge_cue[m]; r_mask[tid]=mask;
    r_u[tid]=content_units[m];
    r_gt[tid]=gt; r_speech[tid]=speech; r_silc[tid]=silc;
    r_resmul[tid]=cold*shortv*speech;
    r_tau[tid]=0.35f*((dur<2.0f)?0.35f:1.0f);
  }
  __syncthreads();

  float pd[4] = {0.f,0.f,0.f,0.f};

  for (int nc = 0; nc < 4; ++nc){
    const int n0 = nc*NT;
    float acc[4][8];
    #pragma unroll
    for (int r=0;r<4;++r)
      #pragma unroll
      for (int c=0;c<8;++c) acc[r][c]=0.f;

    for (int k0 = 0; k0 < DIM_; k0 += KT){
      __syncthreads();   // previous MAC done before overwriting LDS
      // stage feat_W/feat_b slice + B tile (rW1 top rows), independent
      if (tid < 160)      fw_s[tid>>5][tid&31] = feat_W[(tid>>5)*DIM_ + k0 + (tid&31)];
      else if (tid < 192) fb_s[tid-160]        = feat_b[k0 + tid-160];
      #pragma unroll
      for (int p=0;p<4;++p){
        int id = tid + p*256;
        int kr = id >> 5, c4 = (id & 31)*4;
        const float4 v = *reinterpret_cast<const float4*>(&rW1[(k0+kr)*DIM_ + n0 + c4]);
        *reinterpret_cast<float4*>(&Bs[kr][c4]) = v;
      }
      __syncthreads();   // fw_s/fb_s ready
      // compute query tile -> As (transposed)
      #pragma unroll
      for (int p=0;p<8;++p){
        int id = tid + p*256;
        int i = id >> 5, j = id & 31;
        float e = embed[r_u[i]*DIM_ + k0 + j];
        float f = e + r_la[i]*fw_s[0][j] + r_lr[i]*fw_s[1][j] + r_sil[i]*fw_s[2][j]
                    + r_sep[i]*fw_s[3][j] + r_edge[i]*fw_s[4][j] + fb_s[j];
        As[j][i] = tanhf(f)*r_mask[i];
      }
      __syncthreads();   // As, Bs ready
      #pragma unroll
      for (int k=0;k<KT;++k){
        float4 a  = *reinterpret_cast<const float4*>(&As[k][ty*4]);
        float4 b0 = *reinterpret_cast<const float4*>(&Bs[k][tx*8]);
        float4 b1 = *reinterpret_cast<const float4*>(&Bs[k][tx*8+4]);
        float av[4] = {a.x,a.y,a.z,a.w};
        float bv[8] = {b0.x,b0.y,b0.z,b0.w,b1.x,b1.y,b1.z,b1.w};
        #pragma unroll
        for (int r=0;r<4;++r)
          #pragma unroll
          for (int c=0;c<8;++c) acc[r][c] = fmaf(av[r], bv[c], acc[r][c]);
      }
    }
    // epilogue for this n-chunk: add per-n terms, gelu, partial dot with rW2
    const int nb = n0 + tx*8;
    float st[8], wb[8], b1v[8], w2[8];
    #pragma unroll
    for (int c=0;c<8;++c){
      st[c]  = spk_term[b*DIM_ + nb + c];
      wb[c]  = rW1[1024*DIM_ + nb + c];
      b1v[c] = rb1[nb + c];
      w2[c]  = rW2[nb + c];
    }
    #pragma unroll
    for (int r=0;r<4;++r){
      float gt = r_gt[ty*4+r];
      #pragma unroll
      for (int c=0;c<8;++c){
        float x = acc[r][c] + st[c] + gt*wb[c] + b1v[c];
        pd[r] += gelu_exact(x)*w2[c];
      }
    }
  }

  // reduce partial dots across the 16 tx lanes (contiguous lanes in-wave)
  #pragma unroll
  for (int r=0;r<4;++r){
    float v = pd[r];
    v += __shfl_xor(v,1); v += __shfl_xor(v,2);
    v += __shfl_xor(v,4); v += __shfl_xor(v,8);
    if (tx == 0){
      int i = ty*4 + r, m = m0 + i;
      float residual = 0.35f*tanhf(v + rb2[0]) * r_resmul[i];
      float gt = r_gt[i];
      float o = clampf(gt + residual, -1.2f, 1.2f)*r_speech[i]
              + clampf(gt, -r_tau[i], r_tau[i])*r_silc[i];
      out[m] = o;
    }
  }
}

// ---------------------------------------------------------------------------
extern "C" void kernel_launch(void* const* d_in, const int* in_sizes, int n_in,
                              void* d_out, int out_size, void* d_ws, size_t ws_size,
                              hipStream_t stream)
{
  const int*   content_units  = (const int*)  d_in[0];
  const float* log_anchor     = (const float*)d_in[1];
  const float* unit_mask      = (const float*)d_in[2];
  const float* sealed_mask    = (const float*)d_in[3];
  const float* sep_hint       = (const float*)d_in[4];
  const float* edge_cue       = (const float*)d_in[5];
  const float* global_rate    = (const float*)d_in[6];
  const float* local_rate_ema = (const float*)d_in[7];
  const float* silence_mask   = (const float*)d_in[8];
  const float* spk_embed      = (const float*)d_in[9];
  const float* embed          = (const float*)d_in[10];
  const float* feat_W         = (const float*)d_in[11];
  const float* feat_b         = (const float*)d_in[12];
  const float* spk_W          = (const float*)d_in[13];
  const float* spk_b          = (const float*)d_in[14];
  const float* cW1            = (const float*)d_in[15];
  const float* cb1            = (const float*)d_in[16];
  const float* cW2            = (const float*)d_in[17];
  const float* cb2            = (const float*)d_in[18];
  const float* rW1            = (const float*)d_in[19];
  const float* rb1            = (const float*)d_in[20];
  const float* rW2            = (const float*)d_in[21];
  const float* rb2            = (const float*)d_in[22];
  float* out = (float*)d_out;

  float* ws        = (float*)d_ws;
  float* lr_seq    = ws;                 // 32768
  float* prefix    = ws + 32768;         // 32768
  float* spk_ctx   = ws + 65536;         // 8192
  float* spk_term  = ws + 73728;         // 8192
  float* coarse    = ws + 81920;         // 16

  k_scan<<<B_, 64, 0, stream>>>(log_anchor, unit_mask, sealed_mask, silence_mask,
                                local_rate_ema, lr_seq, prefix);
  k_spkctx<<<B_, 512, 0, stream>>>(spk_embed, spk_W, spk_b, spk_ctx);
  k_coarse_spkterm<<<B_, 512, 0, stream>>>(spk_ctx, global_rate, cW1, cb1, cW2, cb2,
                                           rW1, spk_term, coarse);
  k_heavy<<<M_/MT, 256, 0, stream>>>(content_units, log_anchor, unit_mask, sealed_mask,
                                     sep_hint, edge_cue, global_rate, silence_mask,
                                     embed, feat_W, feat_b, rW1, rb1, rW2, rb2,
                                     lr_seq, prefix, spk_term, coarse, out);
}

// Round 2
// 114.294 us; speedup vs baseline: 3.6009x; 3.6009x over previous
//
#include <hip/hip_runtime.h>
#include <math.h>

#define B_   16
#define T_   2048
#define DIM_ 512
#define M_   (B_*T_)

typedef __attribute__((ext_vector_type(8))) short short8_t;   // 8 x bf16 bits
typedef __attribute__((ext_vector_type(4))) float f32x4;

__device__ __forceinline__ float clamp01(float x){ return fminf(fmaxf(x,0.f),1.f); }
__device__ __forceinline__ float clampf(float x,float lo,float hi){ return fminf(fmaxf(x,lo),hi); }
__device__ __forceinline__ float gelu_exact(float x){ return 0.5f*x*(1.f+erff(x*0.70710678118654752f)); }
__device__ __forceinline__ unsigned short bf16_rne(float f){
  unsigned u = __float_as_uint(f);
  unsigned r = (u + 0x7fffu + ((u>>16)&1u)) >> 16;
  return (unsigned short)r;
}
// tanh via native exp2 + rcp; |err| ~1e-6, far below downstream bf16 quantization
__device__ __forceinline__ float fast_tanh(float x){
  float e = __expf(2.0f*x);
  return 1.0f - 2.0f*__builtin_amdgcn_rcpf(e + 1.0f);
}

// ---------------------------------------------------------------------------
// K1: per-batch-row EMA scan (affine wave-scan) + exclusive cumsum(speech)
// ---------------------------------------------------------------------------
__global__ __launch_bounds__(64) void k_scan(
    const float* __restrict__ log_anchor, const float* __restrict__ unit_mask,
    const float* __restrict__ sealed_mask, const float* __restrict__ silence_mask,
    const float* __restrict__ local_rate_ema,
    float* __restrict__ lr_seq, float* __restrict__ prefix_prev)
{
  const int b = blockIdx.x, lane = threadIdx.x;
  const float CE = (float)(1.0 - 0.95);
  const int base = b*T_ + lane*32;

  float A = 1.f, Bv = 0.f, S = 0.f;
  for (int j = 0; j < 32; ++j){
    int idx = base + j;
    float mask   = clamp01(unit_mask[idx]);
    float sealed = clamp01(sealed_mask[idx]);
    float sil    = clamp01(silence_mask[idx])*mask;
    float speech = mask*sealed*(1.f-sil);
    float o  = log_anchor[idx];
    float cm = CE*speech;
    A  = (1.f-cm)*A;
    Bv = (1.f-cm)*Bv + cm*o;
    S += speech;
  }
  float Ai=A, Bi=Bv, Si=S;
  for (int off = 1; off < 64; off <<= 1){
    float Ap=__shfl_up(Ai,off), Bp=__shfl_up(Bi,off), Sp=__shfl_up(Si,off);
    if (lane >= off){ Bi = Ai*Bp + Bi; Ai *= Ap; Si += Sp; }
  }
  float Ae=__shfl_up(Ai,1), Be=__shfl_up(Bi,1), Se=__shfl_up(Si,1);
  if (lane==0){ Ae=1.f; Be=0.f; Se=0.f; }

  float r  = Ae*local_rate_ema[b] + Be;
  float ps = Se;
  for (int j = 0; j < 32; ++j){
    int idx = base + j;
    float mask   = clamp01(unit_mask[idx]);
    float sealed = clamp01(sealed_mask[idx]);
    float sil    = clamp01(silence_mask[idx])*mask;
    float speech = mask*sealed*(1.f-sil);
    float o = log_anchor[idx];
    lr_seq[idx]      = r;
    prefix_prev[idx] = ps;
    r  += CE*speech*(o-r);
    ps += speech;
  }
}

// ---------------------------------------------------------------------------
// K2a: spk_ctx = tanh(spk_embed @ spk_W + spk_b)
// ---------------------------------------------------------------------------
__global__ __launch_bounds__(512) void k_spkctx(
    const float* __restrict__ spk_embed, const float* __restrict__ spk_W,
    const float* __restrict__ spk_b, float* __restrict__ spk_ctx)
{
  __shared__ float se[512];
  const int b = blockIdx.x, n = threadIdx.x;
  se[n] = spk_embed[b*512 + n];
  __syncthreads();
  float acc = spk_b[n];
  #pragma unroll 8
  for (int k = 0; k < 512; ++k) acc = fmaf(se[k], spk_W[k*512 + n], acc);
  spk_ctx[b*512 + n] = tanhf(acc);
}

// ---------------------------------------------------------------------------
// K2b: spk_pb[b,n] = spk_ctx[b,:] @ rW1[512:1024, n] + rb1[n]   (rb1 folded)
//      coarse[b]   = 0.2*tanh( gelu(cctx@cW1+cb1) @ cW2 + cb2 )
// ---------------------------------------------------------------------------
__global__ __launch_bounds__(512) void k_coarse_spkterm(
    const float* __restrict__ spk_ctx, const float* __restrict__ global_rate,
    const float* __restrict__ cW1, const float* __restrict__ cb1,
    const float* __restrict__ cW2, const float* __restrict__ cb2,
    const float* __restrict__ rW1, const float* __restrict__ rb1,
    float* __restrict__ spk_pb, float* __restrict__ coarse)
{
  __shared__ float sc[512];
  __shared__ float red[512];
  const int b = blockIdx.x, n = threadIdx.x;
  sc[n] = spk_ctx[b*512 + n];
  __syncthreads();
  float ac = cb1[n], as = 0.f;
  #pragma unroll 8
  for (int k = 0; k < 512; ++k){
    float s = sc[k];
    ac = fmaf(s, cW1[k*512 + n], ac);
    as = fmaf(s, rW1[(512 + k)*512 + n], as);
  }
  ac = fmaf(global_rate[b], cW1[512*512 + n], ac);
  spk_pb[b*512 + n] = as + rb1[n];
  red[n] = gelu_exact(ac) * cW2[n];
  __syncthreads();
  for (int s = 256; s > 0; s >>= 1){
    if (n < s) red[n] += red[n + s];
    __syncthreads();
  }
  if (n == 0) coarse[b] = 0.2f*tanhf(red[0] + cb2[0]);
}

// ---------------------------------------------------------------------------
// K0: convert rW1[0:512,:] f32 -> bf16, layout Bt[kt][col][kk]  (kt=K/32,
// col=0..511, kk=0..31).  Each K-step slab (32 KB) is contiguous, already
// transposed for MFMA B-fragment reads.
// ---------------------------------------------------------------------------
__global__ __launch_bounds__(256) void k_prep_B(
    const float* __restrict__ rW1, unsigned short* __restrict__ BtG)
{
  const int idx = blockIdx.x*256 + threadIdx.x;   // 8192 = 16 kt * 512 col
  const int col = idx & 511, kt = idx >> 9;
  unsigned q[16];
  #pragma unroll
  for (int p = 0; p < 16; ++p){
    float v0 = rW1[(kt*32 + 2*p    )*512 + col];
    float v1 = rW1[(kt*32 + 2*p + 1)*512 + col];
    q[p] = (unsigned)bf16_rne(v0) | ((unsigned)bf16_rne(v1) << 16);
  }
  uint4* dst = (uint4*)(BtG + kt*16384 + col*32);
  dst[0] = make_uint4(q[0], q[1], q[2], q[3]);
  dst[1] = make_uint4(q[4], q[5], q[6], q[7]);
  dst[2] = make_uint4(q[8], q[9], q[10], q[11]);
  dst[3] = make_uint4(q[12], q[13], q[14], q[15]);
}

// ---------------------------------------------------------------------------
// K3: MFMA heavy kernel. Block = 256 thr (4 waves), 64 rows x all 512 cols.
// Wave w owns cols [w*128, w*128+128). K-loop: 16 steps of 32.
//  - B staged via global_load_lds (preconverted bf16, linear slab)
//  - A (query) computed on the fly -> bf16 LDS, each element exactly once
//  - epilogue: + spk_pb + gt*wb, gelu, dot rW2 (in-register + shfl reduce)
// ---------------------------------------------------------------------------
__global__ __launch_bounds__(256, 2) void k_heavy(
    const int*   __restrict__ content_units, const float* __restrict__ log_anchor,
    const float* __restrict__ unit_mask,     const float* __restrict__ sealed_mask,
    const float* __restrict__ sep_hint,      const float* __restrict__ edge_cue,
    const float* __restrict__ global_rate,   const float* __restrict__ silence_mask,
    const float* __restrict__ embed,         const float* __restrict__ feat_W,
    const float* __restrict__ feat_b,        const float* __restrict__ rW1,
    const float* __restrict__ rW2,           const float* __restrict__ rb2,
    const float* __restrict__ lr_seq,        const float* __restrict__ prefix_prev,
    const float* __restrict__ spk_pb,        const float* __restrict__ coarse,
    const unsigned short* __restrict__ BtG,
    float* __restrict__ out)
{
  __shared__ unsigned short As_s[64*32];    // [row][k]  4 KB
  __shared__ unsigned short Bs_s[512*32];   // [col][k] 32 KB
  __shared__ float r_la[64], r_lr[64], r_sil[64], r_sep[64], r_edge[64], r_mask[64];
  __shared__ int   r_u[64];
  __shared__ float r_gt[64], r_speech[64], r_silc[64], r_resmul[64], r_tau[64];
  __shared__ float pdred[4][64];

  const int m0   = blockIdx.x*64;
  const int b    = m0 >> 11;
  const int tid  = threadIdx.x;
  const int lane = tid & 63;
  const int w    = tid >> 6;
  const int l15  = lane & 15, kg = lane >> 4;

  if (tid < 64){
    int m = m0 + tid;
    float mask   = clamp01(unit_mask[m]);
    float sealed = clamp01(sealed_mask[m]);
    float sil    = clamp01(silence_mask[m])*mask;
    float commit = mask*sealed;
    float silc   = commit*sil;
    float speech = commit*(1.f-sil);
    float la = log_anchor[m];
    float lr = lr_seq[m];
    float gap = clampf(global_rate[b]-lr, -0.35f, 0.35f)*commit;
    float gt  = (gap + coarse[b]*commit)*commit;
    float cold = clamp01(prefix_prev[m]*0.5f);
    float dur  = expf(la);
    float shortv = clamp01(fmaxf(dur,1.f)-1.f);
    r_la[tid]=la; r_lr[tid]=lr; r_sil[tid]=sil;
    r_sep[tid]=sep_hint[m]; r_edge[tid]=edge_cue[m]; r_mask[tid]=mask;
    r_u[tid]=content_units[m];
    r_gt[tid]=gt; r_speech[tid]=speech; r_silc[tid]=silc;
    r_resmul[tid]=cold*shortv*speech;
    r_tau[tid]=0.35f*((dur<2.0f)?0.35f:1.0f);
  }
  __syncthreads();

  f32x4 acc[4][8];
  #pragma unroll
  for (int r=0;r<4;++r)
    #pragma unroll
    for (int c=0;c<8;++c) acc[r][c] = (f32x4)0.0f;

  const int ar = tid >> 2;          // A row this thread computes
  const int aj = (tid & 3) * 8;     // A k-offset within 32-tile
  const int au = r_u[ar];
  const float la=r_la[ar], lr=r_lr[ar], si=r_sil[ar],
              sp=r_sep[ar], ed=r_edge[ar], mk=r_mask[ar];

  for (int kt = 0; kt < 16; ++kt){
    __syncthreads();   // previous step's fragment reads done

    // --- stage B slab (32 KB) : 8 x 1KB issues per wave, linear dest ---
    {
      const unsigned short* src = BtG + kt*16384 + w*4096 + lane*8;
      #pragma unroll
      for (int i=0;i<8;++i){
        __builtin_amdgcn_global_load_lds(
          (const __attribute__((address_space(1))) unsigned int*)(src + i*512),
          (__attribute__((address_space(3))) unsigned int*)(&Bs_s[w*4096 + i*512]),
          16, 0, 0);
      }
    }

    // --- compute A (query) tile: 8 elements per thread ---
    {
      const int jg = kt*32 + aj;
      const float* eb = embed + (size_t)au*DIM_ + jg;
      union { float4 v[2]; float f[8]; } eU, w0U, w1U, w2U, w3U, w4U, bU;
      eU.v[0]  = *(const float4*)(eb);
      eU.v[1]  = *(const float4*)(eb+4);
      w0U.v[0] = *(const float4*)(feat_W + jg);        w0U.v[1] = *(const float4*)(feat_W + jg + 4);
      w1U.v[0] = *(const float4*)(feat_W + 512 + jg);  w1U.v[1] = *(const float4*)(feat_W + 512 + jg + 4);
      w2U.v[0] = *(const float4*)(feat_W + 1024 + jg); w2U.v[1] = *(const float4*)(feat_W + 1024 + jg + 4);
      w3U.v[0] = *(const float4*)(feat_W + 1536 + jg); w3U.v[1] = *(const float4*)(feat_W + 1536 + jg + 4);
      w4U.v[0] = *(const float4*)(feat_W + 2048 + jg); w4U.v[1] = *(const float4*)(feat_W + 2048 + jg + 4);
      bU.v[0]  = *(const float4*)(feat_b + jg);        bU.v[1]  = *(const float4*)(feat_b + jg + 4);
      unsigned pk[4];
      #pragma unroll
      for (int p=0;p<4;++p){
        float fA = eU.f[2*p]   + la*w0U.f[2*p]   + lr*w1U.f[2*p]   + si*w2U.f[2*p]
                 + sp*w3U.f[2*p]   + ed*w4U.f[2*p]   + bU.f[2*p];
        float fB = eU.f[2*p+1] + la*w0U.f[2*p+1] + lr*w1U.f[2*p+1] + si*w2U.f[2*p+1]
                 + sp*w3U.f[2*p+1] + ed*w4U.f[2*p+1] + bU.f[2*p+1];
        float tA = fast_tanh(fA)*mk;
        float tB = fast_tanh(fB)*mk;
        pk[p] = (unsigned)bf16_rne(tA) | ((unsigned)bf16_rne(tB) << 16);
      }
      *(uint4*)&As_s[ar*32 + aj] = make_uint4(pk[0], pk[1], pk[2], pk[3]);
    }

    __syncthreads();   // As/Bs ready (barrier drains vmcnt for global_load_lds)

    // --- fragment reads + 32 MFMAs per wave ---
    short8_t af[4], bfr[8];
    #pragma unroll
    for (int r=0;r<4;++r)
      af[r] = *(const short8_t*)&As_s[(r*16 + l15)*32 + kg*8];
    #pragma unroll
    for (int c=0;c<8;++c)
      bfr[c] = *(const short8_t*)&Bs_s[(w*128 + c*16 + l15)*32 + kg*8];
    #pragma unroll
    for (int r=0;r<4;++r)
      #pragma unroll
      for (int c=0;c<8;++c)
        acc[r][c] = __builtin_amdgcn_mfma_f32_16x16x32_bf16(af[r], bfr[c], acc[r][c], 0, 0, 0);
  }

  // --- epilogue: x = acc + spk_pb[col] + gt[row]*wb[col]; gelu; dot rW2 ---
  const int colb = w*128 + l15;
  float stv[8], wbv[8], w2v[8];
  #pragma unroll
  for (int c=0;c<8;++c){
    int col = colb + c*16;
    stv[c] = spk_pb[b*DIM_ + col];
    wbv[c] = rW1[1024*DIM_ + col];
    w2v[c] = rW2[col];
  }
  #pragma unroll
  for (int r=0;r<4;++r){
    #pragma unroll
    for (int g=0; g<4; ++g){
      int row = r*16 + kg*4 + g;          // C/D layout: row=(lane>>4)*4+reg
      float gt = r_gt[row];
      float s = 0.f;
      #pragma unroll
      for (int c=0;c<8;++c){
        float x = acc[r][c][g] + stv[c] + gt*wbv[c];
        s += gelu_exact(x)*w2v[c];
      }
      s += __shfl_xor(s,1); s += __shfl_xor(s,2);
      s += __shfl_xor(s,4); s += __shfl_xor(s,8);
      if (l15 == 0) pdred[w][row] = s;
    }
  }
  __syncthreads();
  if (tid < 64){
    float v = pdred[0][tid] + pdred[1][tid] + pdred[2][tid] + pdred[3][tid] + rb2[0];
    float residual = 0.35f*tanhf(v) * r_resmul[tid];
    float gt = r_gt[tid];
    out[m0+tid] = clampf(gt + residual, -1.2f, 1.2f)*r_speech[tid]
                + clampf(gt, -r_tau[tid], r_tau[tid])*r_silc[tid];
  }
}

// ---------------------------------------------------------------------------
extern "C" void kernel_launch(void* const* d_in, const int* in_sizes, int n_in,
                              void* d_out, int out_size, void* d_ws, size_t ws_size,
                              hipStream_t stream)
{
  const int*   content_units  = (const int*)  d_in[0];
  const float* log_anchor     = (const float*)d_in[1];
  const float* unit_mask      = (const float*)d_in[2];
  const float* sealed_mask    = (const float*)d_in[3];
  const float* sep_hint       = (const float*)d_in[4];
  const float* edge_cue       = (const float*)d_in[5];
  const float* global_rate    = (const float*)d_in[6];
  const float* local_rate_ema = (const float*)d_in[7];
  const float* silence_mask   = (const float*)d_in[8];
  const float* spk_embed      = (const float*)d_in[9];
  const float* embed          = (const float*)d_in[10];
  const float* feat_W         = (const float*)d_in[11];
  const float* feat_b         = (const float*)d_in[12];
  const float* spk_W          = (const float*)d_in[13];
  const float* spk_b          = (const float*)d_in[14];
  const float* cW1            = (const float*)d_in[15];
  const float* cb1            = (const float*)d_in[16];
  const float* cW2            = (const float*)d_in[17];
  const float* cb2            = (const float*)d_in[18];
  const float* rW1            = (const float*)d_in[19];
  const float* rb1            = (const float*)d_in[20];
  const float* rW2            = (const float*)d_in[21];
  const float* rb2            = (const float*)d_in[22];
  float* out = (float*)d_out;

  // ws layout (floats): lr_seq 32768 | prefix 32768 | spk_ctx 8192 |
  // spk_pb 8192 | coarse 16 | Bt (bf16, 512*512 = 512 KB) @ float-ofs 81936.
  // Total ~848 KB.
  float* ws       = (float*)d_ws;
  float* lr_seq   = ws;
  float* prefix   = ws + 32768;
  float* spk_ctx  = ws + 65536;
  float* spk_pb   = ws + 73728;
  float* coarse   = ws + 81920;
  unsigned short* BtG = (unsigned short*)(ws + 81936);

  k_prep_B<<<32, 256, 0, stream>>>(rW1, BtG);
  k_scan<<<B_, 64, 0, stream>>>(log_anchor, unit_mask, sealed_mask, silence_mask,
                                local_rate_ema, lr_seq, prefix);
  k_spkctx<<<B_, 512, 0, stream>>>(spk_embed, spk_W, spk_b, spk_ctx);
  k_coarse_spkterm<<<B_, 512, 0, stream>>>(spk_ctx, global_rate, cW1, cb1, cW2, cb2,
                                           rW1, rb1, spk_pb, coarse);
  k_heavy<<<M_/64, 256, 0, stream>>>(content_units, log_anchor, unit_mask, sealed_mask,
                                     sep_hint, edge_cue, global_rate, silence_mask,
                                     embed, feat_W, feat_b, rW1, rW2, rb2,
                                     lr_seq, prefix, spk_pb, coarse, BtG, out);
}

// Round 3
// 99.888 us; speedup vs baseline: 4.1202x; 1.1442x over previous
//
#include <hip/hip_runtime.h>
#include <math.h>

#define B_   16
#define T_   2048
#define DIM_ 512
#define M_   (B_*T_)
#define AP   264   // As row stride in shorts (528 B) -> conflict-floor LDS access

typedef __attribute__((ext_vector_type(8))) short short8_t;   // 8 x bf16 bits
typedef __attribute__((ext_vector_type(4))) float f32x4;

__device__ __forceinline__ float clamp01(float x){ return fminf(fmaxf(x,0.f),1.f); }
__device__ __forceinline__ float clampf(float x,float lo,float hi){ return fminf(fmaxf(x,lo),hi); }
__device__ __forceinline__ float gelu_exact(float x){ return 0.5f*x*(1.f+erff(x*0.70710678118654752f)); }
__device__ __forceinline__ unsigned short bf16_rne(float f){
  unsigned u = __float_as_uint(f);
  unsigned r = (u + 0x7fffu + ((u>>16)&1u)) >> 16;
  return (unsigned short)r;
}
__device__ __forceinline__ float fast_tanh(float x){
  float e = __expf(2.0f*x);
  return 1.0f - 2.0f*__builtin_amdgcn_rcpf(e + 1.0f);
}
__device__ __forceinline__ int idx32(int t){ return t + (t>>5); }  // pad stride 33

// ---------------------------------------------------------------------------
// K_pro: fused prologue, one launch, 48 blocks x 512 threads.
//   blocks  0..15 : spk_ctx -> coarse + spk_pb   (b = blk)
//   blocks 16..31 : EMA affine scan + excl cumsum (b = blk-16)
//   blocks 32..47 : rW1[0:512] f32 -> bf16 Bt[kt][col][kk] (kt = blk-32)
// ---------------------------------------------------------------------------
__global__ __launch_bounds__(512) void k_pro(
    const float* __restrict__ log_anchor, const float* __restrict__ unit_mask,
    const float* __restrict__ sealed_mask, const float* __restrict__ silence_mask,
    const float* __restrict__ local_rate_ema, const float* __restrict__ global_rate,
    const float* __restrict__ spk_embed, const float* __restrict__ spk_W,
    const float* __restrict__ spk_b,
    const float* __restrict__ cW1, const float* __restrict__ cb1,
    const float* __restrict__ cW2, const float* __restrict__ cb2,
    const float* __restrict__ rW1, const float* __restrict__ rb1,
    float* __restrict__ lr_seq, float* __restrict__ prefix_prev,
    float* __restrict__ spk_pb, float* __restrict__ coarse,
    unsigned short* __restrict__ BtG)
{
  __shared__ float shbuf[12672];          // 50688 B, max of the three branches
  const int tid = threadIdx.x;
  const int blk = blockIdx.x;

  if (blk < 16){
    // ---- spk_ctx + coarse + spk_pb ----
    const int b = blk, n = tid;
    float* se  = shbuf;
    float* sc  = shbuf + 512;
    float* red = shbuf + 1024;
    se[n] = spk_embed[b*512 + n];
    __syncthreads();
    float acc = spk_b[n];
    #pragma unroll 8
    for (int k = 0; k < 512; ++k) acc = fmaf(se[k], spk_W[k*512 + n], acc);
    float sctx = tanhf(acc);
    sc[n] = sctx;
    __syncthreads();
    float ac = cb1[n], as = 0.f;
    #pragma unroll 8
    for (int k = 0; k < 512; ++k){
      float s = sc[k];
      ac = fmaf(s, cW1[k*512 + n], ac);
      as = fmaf(s, rW1[(512 + k)*512 + n], as);
    }
    ac = fmaf(global_rate[b], cW1[512*512 + n], ac);
    spk_pb[b*512 + n] = as + rb1[n];
    red[n] = gelu_exact(ac) * cW2[n];
    __syncthreads();
    for (int s = 256; s > 0; s >>= 1){
      if (n < s) red[n] += red[n + s];
      __syncthreads();
    }
    if (n == 0) coarse[b] = 0.2f*tanhf(red[0] + cb2[0]);

  } else if (blk < 32){
    // ---- EMA scan (padded-LDS staged, coalesced global IO) ----
    const int b = blk - 16;
    float* s_la = shbuf;             // each padded to 2112 floats
    float* s_um = shbuf + 2112;
    float* s_sm = shbuf + 4224;
    float* s_si = shbuf + 6336;
    float* s_or = shbuf + 8448;
    float* s_op = shbuf + 10560;
    #pragma unroll
    for (int p = 0; p < 4; ++p){
      int t = tid + p*512, g = b*T_ + t, ix = idx32(t);
      s_la[ix] = log_anchor[g];
      s_um[ix] = unit_mask[g];
      s_sm[ix] = sealed_mask[g];
      s_si[ix] = silence_mask[g];
    }
    __syncthreads();
    if (tid < 64){
      const float CE = (float)(1.0 - 0.95);
      const int base = tid*32;
      float A = 1.f, Bv = 0.f, S = 0.f;
      for (int j = 0; j < 32; ++j){
        int ix = idx32(base + j);
        float mask   = clamp01(s_um[ix]);
        float sealed = clamp01(s_sm[ix]);
        float sil    = clamp01(s_si[ix])*mask;
        float speech = mask*sealed*(1.f-sil);
        float cm = CE*speech;
        A  = (1.f-cm)*A;
        Bv = (1.f-cm)*Bv + cm*s_la[ix];
        S += speech;
      }
      float Ai=A, Bi=Bv, Si=S;
      for (int off = 1; off < 64; off <<= 1){
        float Ap=__shfl_up(Ai,off), Bp=__shfl_up(Bi,off), Sp=__shfl_up(Si,off);
        if (tid >= off){ Bi = Ai*Bp + Bi; Ai *= Ap; Si += Sp; }
      }
      float Ae=__shfl_up(Ai,1), Be=__shfl_up(Bi,1), Se=__shfl_up(Si,1);
      if (tid==0){ Ae=1.f; Be=0.f; Se=0.f; }
      float r  = Ae*local_rate_ema[b] + Be;
      float ps = Se;
      for (int j = 0; j < 32; ++j){
        int ix = idx32(base + j);
        float mask   = clamp01(s_um[ix]);
        float sealed = clamp01(s_sm[ix]);
        float sil    = clamp01(s_si[ix])*mask;
        float speech = mask*sealed*(1.f-sil);
        s_or[ix] = r;
        s_op[ix] = ps;
        r  += CE*speech*(s_la[ix]-r);
        ps += speech;
      }
    }
    __syncthreads();
    #pragma unroll
    for (int p = 0; p < 4; ++p){
      int t = tid + p*512, g = b*T_ + t, ix = idx32(t);
      lr_seq[g]      = s_or[ix];
      prefix_prev[g] = s_op[ix];
    }

  } else {
    // ---- B prep: one kt slab (32 k x 512 cols) per block ----
    const int kt = blk - 32;
    unsigned short* sb = (unsigned short*)shbuf;   // [32][512]
    #pragma unroll
    for (int p = 0; p < 32; ++p){
      int id = tid + p*512;
      int kl = id >> 9, col = id & 511;
      sb[kl*512 + col] = bf16_rne(rW1[(kt*32 + kl)*512 + col]);
    }
    __syncthreads();
    const int col = tid;
    unsigned q[16];
    #pragma unroll
    for (int p = 0; p < 16; ++p)
      q[p] = (unsigned)sb[(2*p)*512 + col] | ((unsigned)sb[(2*p+1)*512 + col] << 16);
    uint4* dst = (uint4*)(BtG + kt*16384 + col*32);
    dst[0] = make_uint4(q[0], q[1], q[2], q[3]);
    dst[1] = make_uint4(q[4], q[5], q[6], q[7]);
    dst[2] = make_uint4(q[8], q[9], q[10], q[11]);
    dst[3] = make_uint4(q[12], q[13], q[14], q[15]);
  }
}

// ---------------------------------------------------------------------------
// K3: MFMA heavy kernel. Block = 4 waves, 64 rows x all 512 cols.
//  - A computed in 2 half-tiles (64x256 bf16) into padded LDS -> 4 barriers
//  - B fragments loaded straight from L2 (BtG pre-transposed) into regs
//  - kt-loop is barrier-free: ds_read A + global B + 32 MFMA per wave
// ---------------------------------------------------------------------------
__global__ __launch_bounds__(256, 2) void k_heavy(
    const int*   __restrict__ content_units, const float* __restrict__ log_anchor,
    const float* __restrict__ unit_mask,     const float* __restrict__ sealed_mask,
    const float* __restrict__ sep_hint,      const float* __restrict__ edge_cue,
    const float* __restrict__ global_rate,   const float* __restrict__ silence_mask,
    const float* __restrict__ embed,         const float* __restrict__ feat_W,
    const float* __restrict__ feat_b,        const float* __restrict__ rW1,
    const float* __restrict__ rW2,           const float* __restrict__ rb2,
    const float* __restrict__ lr_seq,        const float* __restrict__ prefix_prev,
    const float* __restrict__ spk_pb,        const float* __restrict__ coarse,
    const unsigned short* __restrict__ BtG,
    float* __restrict__ out)
{
  __shared__ unsigned short As_s[64*AP];    // 33792 B
  __shared__ float r_la[64], r_lr[64], r_sil[64], r_sep[64], r_edge[64], r_mask[64];
  __shared__ int   r_u[64];
  __shared__ float r_gt[64], r_speech[64], r_silc[64], r_resmul[64], r_tau[64];
  __shared__ float pdred[4][64];

  const int m0   = blockIdx.x*64;
  const int b    = m0 >> 11;
  const int tid  = threadIdx.x;
  const int lane = tid & 63;
  const int w    = tid >> 6;
  const int l15  = lane & 15, kg = lane >> 4;

  if (tid < 64){
    int m = m0 + tid;
    float mask   = clamp01(unit_mask[m]);
    float sealed = clamp01(sealed_mask[m]);
    float sil    = clamp01(silence_mask[m])*mask;
    float commit = mask*sealed;
    float silc   = commit*sil;
    float speech = commit*(1.f-sil);
    float la = log_anchor[m];
    float lr = lr_seq[m];
    float gap = clampf(global_rate[b]-lr, -0.35f, 0.35f)*commit;
    float gt  = (gap + coarse[b]*commit)*commit;
    float cold = clamp01(prefix_prev[m]*0.5f);
    float dur  = expf(la);
    float shortv = clamp01(fmaxf(dur,1.f)-1.f);
    r_la[tid]=la; r_lr[tid]=lr; r_sil[tid]=sil;
    r_sep[tid]=sep_hint[m]; r_edge[tid]=edge_cue[m]; r_mask[tid]=mask;
    r_u[tid]=content_units[m];
    r_gt[tid]=gt; r_speech[tid]=speech; r_silc[tid]=silc;
    r_resmul[tid]=cold*shortv*speech;
    r_tau[tid]=0.35f*((dur<2.0f)?0.35f:1.0f);
  }
  __syncthreads();

  f32x4 acc[4][8];
  #pragma unroll
  for (int r=0;r<4;++r)
    #pragma unroll
    for (int c=0;c<8;++c) acc[r][c] = (f32x4)0.0f;

  // A-compute assignment: 4 threads per row; thread handles chunks
  // c = (tid&3) + 4j (16B each) -> 16-line embed gathers, conflict-floor LDS
  const int ar = tid >> 2;
  const int c0 = tid & 3;
  const int au = r_u[ar];
  const float la=r_la[ar], lr=r_lr[ar], si=r_sil[ar],
              sp=r_sep[ar], ed=r_edge[ar], mk=r_mask[ar];
  const unsigned short* bwave = BtG + (w*128 + l15)*32 + kg*8;

  for (int h = 0; h < 2; ++h){
    __syncthreads();   // As free (prev half's fragment reads done)
    #pragma unroll
    for (int j = 0; j < 8; ++j){
      const int c  = c0 + 4*j;             // chunk 0..31 within half
      const int jg = h*256 + c*8;          // global k
      union { float4 v[2]; float f[8]; } eU, w0U, w1U, w2U, w3U, w4U, bU;
      const float* eb = embed + (size_t)au*DIM_ + jg;
      eU.v[0]  = *(const float4*)(eb);
      eU.v[1]  = *(const float4*)(eb+4);
      w0U.v[0] = *(const float4*)(feat_W + jg);        w0U.v[1] = *(const float4*)(feat_W + jg + 4);
      w1U.v[0] = *(const float4*)(feat_W + 512 + jg);  w1U.v[1] = *(const float4*)(feat_W + 512 + jg + 4);
      w2U.v[0] = *(const float4*)(feat_W + 1024 + jg); w2U.v[1] = *(const float4*)(feat_W + 1024 + jg + 4);
      w3U.v[0] = *(const float4*)(feat_W + 1536 + jg); w3U.v[1] = *(const float4*)(feat_W + 1536 + jg + 4);
      w4U.v[0] = *(const float4*)(feat_W + 2048 + jg); w4U.v[1] = *(const float4*)(feat_W + 2048 + jg + 4);
      bU.v[0]  = *(const float4*)(feat_b + jg);        bU.v[1]  = *(const float4*)(feat_b + jg + 4);
      unsigned pk[4];
      #pragma unroll
      for (int p=0;p<4;++p){
        float fA = eU.f[2*p]   + la*w0U.f[2*p]   + lr*w1U.f[2*p]   + si*w2U.f[2*p]
                 + sp*w3U.f[2*p]   + ed*w4U.f[2*p]   + bU.f[2*p];
        float fB = eU.f[2*p+1] + la*w0U.f[2*p+1] + lr*w1U.f[2*p+1] + si*w2U.f[2*p+1]
                 + sp*w3U.f[2*p+1] + ed*w4U.f[2*p+1] + bU.f[2*p+1];
        pk[p] = (unsigned)bf16_rne(fast_tanh(fA)*mk)
              | ((unsigned)bf16_rne(fast_tanh(fB)*mk) << 16);
      }
      *(uint4*)&As_s[ar*AP + c*8] = make_uint4(pk[0], pk[1], pk[2], pk[3]);
    }
    __syncthreads();   // As ready

    #pragma unroll 2
    for (int kt8 = 0; kt8 < 8; ++kt8){
      const unsigned short* bkt = bwave + (h*8 + kt8)*16384;
      short8_t af[4], bfr[8];
      #pragma unroll
      for (int r=0;r<4;++r)
        af[r] = *(const short8_t*)&As_s[(r*16 + l15)*AP + kt8*32 + kg*8];
      #pragma unroll
      for (int c=0;c<8;++c)
        bfr[c] = *(const short8_t*)(bkt + c*512);
      #pragma unroll
      for (int r=0;r<4;++r)
        #pragma unroll
        for (int c=0;c<8;++c)
          acc[r][c] = __builtin_amdgcn_mfma_f32_16x16x32_bf16(af[r], bfr[c], acc[r][c], 0, 0, 0);
    }
  }

  // --- epilogue: x = acc + spk_pb[col] + gt[row]*wb[col]; gelu; dot rW2 ---
  const int colb = w*128 + l15;
  float stv[8], wbv[8], w2v[8];
  #pragma unroll
  for (int c=0;c<8;++c){
    int col = colb + c*16;
    stv[c] = spk_pb[b*DIM_ + col];
    wbv[c] = rW1[1024*DIM_ + col];
    w2v[c] = rW2[col];
  }
  #pragma unroll
  for (int r=0;r<4;++r){
    #pragma unroll
    for (int g=0; g<4; ++g){
      int row = r*16 + kg*4 + g;           // C/D: row=(lane>>4)*4+reg
      float gt = r_gt[row];
      float s = 0.f;
      #pragma unroll
      for (int c=0;c<8;++c){
        float x = acc[r][c][g] + stv[c] + gt*wbv[c];
        s += gelu_exact(x)*w2v[c];
      }
      s += __shfl_xor(s,1); s += __shfl_xor(s,2);
      s += __shfl_xor(s,4); s += __shfl_xor(s,8);
      if (l15 == 0) pdred[w][row] = s;
    }
  }
  __syncthreads();
  if (tid < 64){
    float v = pdred[0][tid] + pdred[1][tid] + pdred[2][tid] + pdred[3][tid] + rb2[0];
    float residual = 0.35f*tanhf(v) * r_resmul[tid];
    float gt = r_gt[tid];
    out[m0+tid] = clampf(gt + residual, -1.2f, 1.2f)*r_speech[tid]
                + clampf(gt, -r_tau[tid], r_tau[tid])*r_silc[tid];
  }
}

// ---------------------------------------------------------------------------
extern "C" void kernel_launch(void* const* d_in, const int* in_sizes, int n_in,
                              void* d_out, int out_size, void* d_ws, size_t ws_size,
                              hipStream_t stream)
{
  const int*   content_units  = (const int*)  d_in[0];
  const float* log_anchor     = (const float*)d_in[1];
  const float* unit_mask      = (const float*)d_in[2];
  const float* sealed_mask    = (const float*)d_in[3];
  const float* sep_hint       = (const float*)d_in[4];
  const float* edge_cue       = (const float*)d_in[5];
  const float* global_rate    = (const float*)d_in[6];
  const float* local_rate_ema = (const float*)d_in[7];
  const float* silence_mask   = (const float*)d_in[8];
  const float* spk_embed      = (const float*)d_in[9];
  const float* embed          = (const float*)d_in[10];
  const float* feat_W         = (const float*)d_in[11];
  const float* feat_b         = (const float*)d_in[12];
  const float* spk_W          = (const float*)d_in[13];
  const float* spk_b          = (const float*)d_in[14];
  const float* cW1            = (const float*)d_in[15];
  const float* cb1            = (const float*)d_in[16];
  const float* cW2            = (const float*)d_in[17];
  const float* cb2            = (const float*)d_in[18];
  const float* rW1            = (const float*)d_in[19];
  const float* rb1            = (const float*)d_in[20];
  const float* rW2            = (const float*)d_in[21];
  const float* rb2            = (const float*)d_in[22];
  float* out = (float*)d_out;

  float* ws       = (float*)d_ws;
  float* lr_seq   = ws;                  // 32768
  float* prefix   = ws + 32768;          // 32768
  float* spk_pb   = ws + 65536;          // 8192
  float* coarse   = ws + 73728;          // 16
  unsigned short* BtG = (unsigned short*)(ws + 73744);   // 512 KB bf16

  k_pro<<<48, 512, 0, stream>>>(log_anchor, unit_mask, sealed_mask, silence_mask,
                                local_rate_ema, global_rate, spk_embed, spk_W, spk_b,
                                cW1, cb1, cW2, cb2, rW1, rb1,
                                lr_seq, prefix, spk_pb, coarse, BtG);
  k_heavy<<<M_/64, 256, 0, stream>>>(content_units, log_anchor, unit_mask, sealed_mask,
                                     sep_hint, edge_cue, global_rate, silence_mask,
                                     embed, feat_W, feat_b, rW1, rW2, rb2,
                                     lr_seq, prefix, spk_pb, coarse, BtG, out);
}

// Round 4
// 52.834 us; speedup vs baseline: 7.7897x; 1.8906x over previous
//
#include <hip/hip_runtime.h>
#include <math.h>

#define B_   16
#define T_   2048
#define DIM_ 512
#define M_   (B_*T_)
#define AP   520   // As row stride in shorts (1040 B) -> bank-floor LDS access

typedef __attribute__((ext_vector_type(8))) short short8_t;   // 8 x bf16 bits
typedef __attribute__((ext_vector_type(4))) float f32x4;

__device__ __forceinline__ float clamp01(float x){ return fminf(fmaxf(x,0.f),1.f); }
__device__ __forceinline__ float clampf(float x,float lo,float hi){ return fminf(fmaxf(x,lo),hi); }
__device__ __forceinline__ float gelu_exact(float x){ return 0.5f*x*(1.f+erff(x*0.70710678118654752f)); }
__device__ __forceinline__ unsigned short bf16_rne(float f){
  unsigned u = __float_as_uint(f);
  unsigned r = (u + 0x7fffu + ((u>>16)&1u)) >> 16;
  return (unsigned short)r;
}
__device__ __forceinline__ float fast_tanh(float x){
  float e = __expf(2.0f*x);
  return 1.0f - 2.0f*__builtin_amdgcn_rcpf(e + 1.0f);
}
__device__ __forceinline__ int idx32(int t){ return t + (t>>5); }  // pad stride 33

// ---------------------------------------------------------------------------
// P1: 160 blocks x 512 threads.
//  blk   0..127 : spk_ctx[b, s*64 .. s*64+64)  (b=blk>>3, s=blk&7)
//  blk 128..143 : EMA scan + excl cumsum       (b=blk-128)
//  blk 144..159 : rW1[0:512] -> bf16 Bt[kt][col][kk]  (kt=blk-144)
// ---------------------------------------------------------------------------
__global__ __launch_bounds__(512) void k_p1(
    const float* __restrict__ log_anchor, const float* __restrict__ unit_mask,
    const float* __restrict__ sealed_mask, const float* __restrict__ silence_mask,
    const float* __restrict__ local_rate_ema,
    const float* __restrict__ spk_embed, const float* __restrict__ spk_W,
    const float* __restrict__ spk_b, const float* __restrict__ rW1,
    float* __restrict__ lr_seq, float* __restrict__ prefix_prev,
    float* __restrict__ spk_ctx, unsigned short* __restrict__ BtG)
{
  __shared__ float shbuf[12672];
  const int tid = threadIdx.x;
  const int blk = blockIdx.x;

  if (blk < 128){
    // ---- spk_ctx slice: 64 cols, K split 32-way ----
    const int b = blk >> 3, n0 = (blk & 7)*64;
    float* se      = shbuf;          // 512
    float* partial = shbuf + 512;    // 32*64
    se[tid] = spk_embed[b*512 + tid];
    __syncthreads();
    const int nq = tid & 15, q = tid >> 4;     // q = 0..31, k in [q*16, q*16+16)
    float a0=0.f, a1=0.f, a2=0.f, a3=0.f;
    const float* wp = spk_W + (q*16)*512 + n0 + nq*4;
    #pragma unroll
    for (int kk = 0; kk < 16; ++kk){
      float s = se[q*16 + kk];
      float4 v = *(const float4*)(wp + kk*512);
      a0 = fmaf(s, v.x, a0); a1 = fmaf(s, v.y, a1);
      a2 = fmaf(s, v.z, a2); a3 = fmaf(s, v.w, a3);
    }
    *(float4*)&partial[q*64 + nq*4] = make_float4(a0,a1,a2,a3);
    __syncthreads();
    if (tid < 64){
      float acc = spk_b[n0 + tid];
      #pragma unroll
      for (int qq = 0; qq < 32; ++qq) acc += partial[qq*64 + tid];
      spk_ctx[b*512 + n0 + tid] = tanhf(acc);
    }

  } else if (blk < 144){
    // ---- EMA scan (padded-LDS staged, coalesced global IO) ----
    const int b = blk - 128;
    float* s_la = shbuf;
    float* s_um = shbuf + 2112;
    float* s_sm = shbuf + 4224;
    float* s_si = shbuf + 6336;
    float* s_or = shbuf + 8448;
    float* s_op = shbuf + 10560;
    #pragma unroll
    for (int p = 0; p < 4; ++p){
      int t = tid + p*512, g = b*T_ + t, ix = idx32(t);
      s_la[ix] = log_anchor[g];
      s_um[ix] = unit_mask[g];
      s_sm[ix] = sealed_mask[g];
      s_si[ix] = silence_mask[g];
    }
    __syncthreads();
    if (tid < 64){
      const float CE = (float)(1.0 - 0.95);
      const int base = tid*32;
      float A = 1.f, Bv = 0.f, S = 0.f;
      for (int j = 0; j < 32; ++j){
        int ix = idx32(base + j);
        float mask   = clamp01(s_um[ix]);
        float sealed = clamp01(s_sm[ix]);
        float sil    = clamp01(s_si[ix])*mask;
        float speech = mask*sealed*(1.f-sil);
        float cm = CE*speech;
        A  = (1.f-cm)*A;
        Bv = (1.f-cm)*Bv + cm*s_la[ix];
        S += speech;
      }
      float Ai=A, Bi=Bv, Si=S;
      for (int off = 1; off < 64; off <<= 1){
        float Ap=__shfl_up(Ai,off), Bp=__shfl_up(Bi,off), Sp=__shfl_up(Si,off);
        if (tid >= off){ Bi = Ai*Bp + Bi; Ai *= Ap; Si += Sp; }
      }
      float Ae=__shfl_up(Ai,1), Be=__shfl_up(Bi,1), Se=__shfl_up(Si,1);
      if (tid==0){ Ae=1.f; Be=0.f; Se=0.f; }
      float r  = Ae*local_rate_ema[b] + Be;
      float ps = Se;
      for (int j = 0; j < 32; ++j){
        int ix = idx32(base + j);
        float mask   = clamp01(s_um[ix]);
        float sealed = clamp01(s_sm[ix]);
        float sil    = clamp01(s_si[ix])*mask;
        float speech = mask*sealed*(1.f-sil);
        s_or[ix] = r;
        s_op[ix] = ps;
        r  += CE*speech*(s_la[ix]-r);
        ps += speech;
      }
    }
    __syncthreads();
    #pragma unroll
    for (int p = 0; p < 4; ++p){
      int t = tid + p*512, g = b*T_ + t, ix = idx32(t);
      lr_seq[g]      = s_or[ix];
      prefix_prev[g] = s_op[ix];
    }

  } else {
    // ---- B prep: one kt slab (32 k x 512 cols) per block ----
    const int kt = blk - 144;
    unsigned short* sb = (unsigned short*)shbuf;   // [32][512]
    #pragma unroll
    for (int p = 0; p < 32; ++p){
      int id = tid + p*512;
      int kl = id >> 9, col = id & 511;
      sb[kl*512 + col] = bf16_rne(rW1[(kt*32 + kl)*512 + col]);
    }
    __syncthreads();
    const int col = tid;
    unsigned q[16];
    #pragma unroll
    for (int p = 0; p < 16; ++p)
      q[p] = (unsigned)sb[(2*p)*512 + col] | ((unsigned)sb[(2*p+1)*512 + col] << 16);
    uint4* dst = (uint4*)(BtG + kt*16384 + col*32);
    dst[0] = make_uint4(q[0], q[1], q[2], q[3]);
    dst[1] = make_uint4(q[4], q[5], q[6], q[7]);
    dst[2] = make_uint4(q[8], q[9], q[10], q[11]);
    dst[3] = make_uint4(q[12], q[13], q[14], q[15]);
  }
}

// ---------------------------------------------------------------------------
// P2: 256 blocks x 512 threads.
//  blk   0..127 : spk_pb[b, slice] = sc@rW1[512:1024,slice] + rb1
//  blk 128..255 : cpart[b][s] = sum_slice gelu(ac)*cW2   (coarse partials)
// ---------------------------------------------------------------------------
__global__ __launch_bounds__(512) void k_p2(
    const float* __restrict__ spk_ctx, const float* __restrict__ global_rate,
    const float* __restrict__ cW1, const float* __restrict__ cb1,
    const float* __restrict__ cW2, const float* __restrict__ rW1,
    const float* __restrict__ rb1,
    float* __restrict__ spk_pb, float* __restrict__ cpart)
{
  __shared__ float sc[512];
  __shared__ float partial[32*64];
  const int tid = threadIdx.x;
  const int blk = blockIdx.x;
  const bool isAC = blk >= 128;
  const int bb = isAC ? (blk - 128) : blk;
  const int b = bb >> 3, s = bb & 7, n0 = s*64;

  sc[tid] = spk_ctx[b*512 + tid];
  __syncthreads();
  const int nq = tid & 15, q = tid >> 4;
  const float* mat = isAC ? cW1 : (rW1 + 512*512);
  float a0=0.f, a1=0.f, a2=0.f, a3=0.f;
  const float* wp = mat + (q*16)*512 + n0 + nq*4;
  #pragma unroll
  for (int kk = 0; kk < 16; ++kk){
    float sv = sc[q*16 + kk];
    float4 v = *(const float4*)(wp + kk*512);
    a0 = fmaf(sv, v.x, a0); a1 = fmaf(sv, v.y, a1);
    a2 = fmaf(sv, v.z, a2); a3 = fmaf(sv, v.w, a3);
  }
  *(float4*)&partial[q*64 + nq*4] = make_float4(a0,a1,a2,a3);
  __syncthreads();
  if (tid < 64){
    const int n = n0 + tid;
    float acc = 0.f;
    #pragma unroll
    for (int qq = 0; qq < 32; ++qq) acc += partial[qq*64 + tid];
    if (!isAC){
      spk_pb[b*512 + n] = acc + rb1[n];
    } else {
      float ac = acc + cb1[n] + global_rate[b]*cW1[512*512 + n];
      float g  = gelu_exact(ac)*cW2[n];
      g += __shfl_xor(g,1);  g += __shfl_xor(g,2);  g += __shfl_xor(g,4);
      g += __shfl_xor(g,8);  g += __shfl_xor(g,16); g += __shfl_xor(g,32);
      if (tid == 0) cpart[b*8 + s] = g;
    }
  }
}

// ---------------------------------------------------------------------------
// K3: MFMA heavy kernel. Block = 4 waves, 64 rows x all 512 cols.
//  - full-K A tile (64x512 bf16) computed once -> 2 barriers/block
//  - A-compute: thread = 8 rows x 2 chunks -> feat loads amortized 8x
//  - kt-loop barrier-free: ds_read A + L2 B fragments + 32 MFMA
// ---------------------------------------------------------------------------
__global__ __launch_bounds__(256, 2) void k_heavy(
    const int*   __restrict__ content_units, const float* __restrict__ log_anchor,
    const float* __restrict__ unit_mask,     const float* __restrict__ sealed_mask,
    const float* __restrict__ sep_hint,      const float* __restrict__ edge_cue,
    const float* __restrict__ global_rate,   const float* __restrict__ silence_mask,
    const float* __restrict__ embed,         const float* __restrict__ feat_W,
    const float* __restrict__ feat_b,        const float* __restrict__ rW1,
    const float* __restrict__ rW2,           const float* __restrict__ rb2,
    const float* __restrict__ cb2,
    const float* __restrict__ lr_seq,        const float* __restrict__ prefix_prev,
    const float* __restrict__ spk_pb,        const float* __restrict__ cpart,
    const unsigned short* __restrict__ BtG,
    float* __restrict__ out)
{
  __shared__ unsigned short As_s[64*AP];    // 66560 B
  __shared__ float r_la[64], r_lr[64], r_sil[64], r_sep[64], r_edge[64], r_mask[64];
  __shared__ int   r_u[64];
  __shared__ float r_gt[64], r_speech[64], r_silc[64], r_resmul[64], r_tau[64];
  __shared__ float pdred[4][64];

  const int m0   = blockIdx.x*64;
  const int b    = m0 >> 11;
  const int tid  = threadIdx.x;
  const int lane = tid & 63;
  const int w    = tid >> 6;
  const int l15  = lane & 15, kg = lane >> 4;

  if (tid < 64){
    int m = m0 + tid;
    float csum = cb2[0];
    #pragma unroll
    for (int s = 0; s < 8; ++s) csum += cpart[b*8 + s];
    float coarse = 0.2f*tanhf(csum);
    float mask   = clamp01(unit_mask[m]);
    float sealed = clamp01(sealed_mask[m]);
    float sil    = clamp01(silence_mask[m])*mask;
    float commit = mask*sealed;
    float silc   = commit*sil;
    float speech = commit*(1.f-sil);
    float la = log_anchor[m];
    float lr = lr_seq[m];
    float gap = clampf(global_rate[b]-lr, -0.35f, 0.35f)*commit;
    float gt  = (gap + coarse*commit)*commit;
    float cold = clamp01(prefix_prev[m]*0.5f);
    float dur  = expf(la);
    float shortv = clamp01(fmaxf(dur,1.f)-1.f);
    r_la[tid]=la; r_lr[tid]=lr; r_sil[tid]=sil;
    r_sep[tid]=sep_hint[m]; r_edge[tid]=edge_cue[m]; r_mask[tid]=mask;
    r_u[tid]=content_units[m];
    r_gt[tid]=gt; r_speech[tid]=speech; r_silc[tid]=silc;
    r_resmul[tid]=cold*shortv*speech;
    r_tau[tid]=0.35f*((dur<2.0f)?0.35f:1.0f);
  }
  __syncthreads();

  // ---- A-compute: full K, thread = rows rg..rg+7 x chunks cp, cp+1 ----
  {
    const int rg = (tid >> 5)*8;
    const int cp = (tid & 31)*2;
    #pragma unroll
    for (int j = 0; j < 2; ++j){
      const int c  = cp + j;
      const int jg = c*8;
      union { float4 v[2]; float f[8]; } w0U, w1U, w2U, w3U, w4U, bU;
      w0U.v[0] = *(const float4*)(feat_W + jg);        w0U.v[1] = *(const float4*)(feat_W + jg + 4);
      w1U.v[0] = *(const float4*)(feat_W + 512 + jg);  w1U.v[1] = *(const float4*)(feat_W + 512 + jg + 4);
      w2U.v[0] = *(const float4*)(feat_W + 1024 + jg); w2U.v[1] = *(const float4*)(feat_W + 1024 + jg + 4);
      w3U.v[0] = *(const float4*)(feat_W + 1536 + jg); w3U.v[1] = *(const float4*)(feat_W + 1536 + jg + 4);
      w4U.v[0] = *(const float4*)(feat_W + 2048 + jg); w4U.v[1] = *(const float4*)(feat_W + 2048 + jg + 4);
      bU.v[0]  = *(const float4*)(feat_b + jg);        bU.v[1]  = *(const float4*)(feat_b + jg + 4);
      #pragma unroll
      for (int i = 0; i < 8; ++i){
        const int row = rg + i;
        const int u   = r_u[row];
        const float la=r_la[row], lr=r_lr[row], si=r_sil[row],
                    sp=r_sep[row], ed=r_edge[row], mk=r_mask[row];
        union { float4 v[2]; float f[8]; } eU;
        const float* eb = embed + (size_t)u*DIM_ + jg;
        eU.v[0] = *(const float4*)eb;
        eU.v[1] = *(const float4*)(eb + 4);
        unsigned pk[4];
        #pragma unroll
        for (int p = 0; p < 4; ++p){
          float fA = eU.f[2*p]   + bU.f[2*p]   + la*w0U.f[2*p]   + lr*w1U.f[2*p]
                   + si*w2U.f[2*p]   + sp*w3U.f[2*p]   + ed*w4U.f[2*p];
          float fB = eU.f[2*p+1] + bU.f[2*p+1] + la*w0U.f[2*p+1] + lr*w1U.f[2*p+1]
                   + si*w2U.f[2*p+1] + sp*w3U.f[2*p+1] + ed*w4U.f[2*p+1];
          pk[p] = (unsigned)bf16_rne(fast_tanh(fA)*mk)
                | ((unsigned)bf16_rne(fast_tanh(fB)*mk) << 16);
        }
        *(uint4*)&As_s[row*AP + c*8] = make_uint4(pk[0], pk[1], pk[2], pk[3]);
      }
    }
  }
  __syncthreads();   // As ready; no more barriers until epilogue

  f32x4 acc[4][8];
  #pragma unroll
  for (int r=0;r<4;++r)
    #pragma unroll
    for (int c=0;c<8;++c) acc[r][c] = (f32x4)0.0f;

  const unsigned short* bwave = BtG + (w*128 + l15)*32 + kg*8;

  #pragma unroll 4
  for (int kt = 0; kt < 16; ++kt){
    const unsigned short* bkt = bwave + kt*16384;
    short8_t af[4], bfr[8];
    #pragma unroll
    for (int r=0;r<4;++r)
      af[r] = *(const short8_t*)&As_s[(r*16 + l15)*AP + kt*32 + kg*8];
    #pragma unroll
    for (int c=0;c<8;++c)
      bfr[c] = *(const short8_t*)(bkt + c*512);
    #pragma unroll
    for (int r=0;r<4;++r)
      #pragma unroll
      for (int c=0;c<8;++c)
        acc[r][c] = __builtin_amdgcn_mfma_f32_16x16x32_bf16(af[r], bfr[c], acc[r][c], 0, 0, 0);
  }

  // --- epilogue: x = acc + spk_pb[col] + gt[row]*wb[col]; gelu; dot rW2 ---
  const int colb = w*128 + l15;
  float stv[8], wbv[8], w2v[8];
  #pragma unroll
  for (int c=0;c<8;++c){
    int col = colb + c*16;
    stv[c] = spk_pb[b*DIM_ + col];
    wbv[c] = rW1[1024*DIM_ + col];
    w2v[c] = rW2[col];
  }
  #pragma unroll
  for (int r=0;r<4;++r){
    #pragma unroll
    for (int g=0; g<4; ++g){
      int row = r*16 + kg*4 + g;           // C/D: row=(lane>>4)*4+reg
      float gt = r_gt[row];
      float s = 0.f;
      #pragma unroll
      for (int c=0;c<8;++c){
        float x = acc[r][c][g] + stv[c] + gt*wbv[c];
        s += gelu_exact(x)*w2v[c];
      }
      s += __shfl_xor(s,1); s += __shfl_xor(s,2);
      s += __shfl_xor(s,4); s += __shfl_xor(s,8);
      if (l15 == 0) pdred[w][row] = s;
    }
  }
  __syncthreads();
  if (tid < 64){
    float v = pdred[0][tid] + pdred[1][tid] + pdred[2][tid] + pdred[3][tid] + rb2[0];
    float residual = 0.35f*tanhf(v) * r_resmul[tid];
    float gt = r_gt[tid];
    out[m0+tid] = clampf(gt + residual, -1.2f, 1.2f)*r_speech[tid]
                + clampf(gt, -r_tau[tid], r_tau[tid])*r_silc[tid];
  }
}

// ---------------------------------------------------------------------------
extern "C" void kernel_launch(void* const* d_in, const int* in_sizes, int n_in,
                              void* d_out, int out_size, void* d_ws, size_t ws_size,
                              hipStream_t stream)
{
  const int*   content_units  = (const int*)  d_in[0];
  const float* log_anchor     = (const float*)d_in[1];
  const float* unit_mask      = (const float*)d_in[2];
  const float* sealed_mask    = (const float*)d_in[3];
  const float* sep_hint       = (const float*)d_in[4];
  const float* edge_cue       = (const float*)d_in[5];
  const float* global_rate    = (const float*)d_in[6];
  const float* local_rate_ema = (const float*)d_in[7];
  const float* silence_mask   = (const float*)d_in[8];
  const float* spk_embed      = (const float*)d_in[9];
  const float* embed          = (const float*)d_in[10];
  const float* feat_W         = (const float*)d_in[11];
  const float* feat_b         = (const float*)d_in[12];
  const float* spk_W          = (const float*)d_in[13];
  const float* spk_b          = (const float*)d_in[14];
  const float* cW1            = (const float*)d_in[15];
  const float* cb1            = (const float*)d_in[16];
  const float* cW2            = (const float*)d_in[17];
  const float* cb2            = (const float*)d_in[18];
  const float* rW1            = (const float*)d_in[19];
  const float* rb1            = (const float*)d_in[20];
  const float* rW2            = (const float*)d_in[21];
  const float* rb2            = (const float*)d_in[22];
  float* out = (float*)d_out;

  float* ws       = (float*)d_ws;
  float* lr_seq   = ws;                  // 32768
  float* prefix   = ws + 32768;          // 32768
  float* spk_ctx  = ws + 65536;          // 8192
  float* spk_pb   = ws + 73728;          // 8192
  float* cpart    = ws + 81920;          // 128
  unsigned short* BtG = (unsigned short*)(ws + 82048);   // 512 KB bf16

  k_p1<<<160, 512, 0, stream>>>(log_anchor, unit_mask, sealed_mask, silence_mask,
                                local_rate_ema, spk_embed, spk_W, spk_b, rW1,
                                lr_seq, prefix, spk_ctx, BtG);
  k_p2<<<256, 512, 0, stream>>>(spk_ctx, global_rate, cW1, cb1, cW2, rW1, rb1,
                                spk_pb, cpart);
  k_heavy<<<M_/64, 256, 0, stream>>>(content_units, log_anchor, unit_mask, sealed_mask,
                                     sep_hint, edge_cue, global_rate, silence_mask,
                                     embed, feat_W, feat_b, rW1, rW2, rb2, cb2,
                                     lr_seq, prefix, spk_pb, cpart, BtG, out);
}